// Round 1
// baseline (306.379 us; speedup 1.0000x reference)
//
#include <hip/hip_runtime.h>
#include <math.h>

#define NA 8
#define SS 512
#define N1 160
#define BROWS 32
#define NTHREADS 320

typedef __attribute__((ext_vector_type(8))) short bf16x8;
typedef __attribute__((ext_vector_type(4))) float f32x4;

static __device__ __forceinline__ unsigned short f2bf(float f) {
    union { float f; unsigned u; } v; v.f = f;
    unsigned r = v.u + 0x7FFFu + ((v.u >> 16) & 1u);
    return (unsigned short)(r >> 16);
}
static __device__ __forceinline__ float bf2f(unsigned short u) {
    union { unsigned u; float f; } v; v.u = ((unsigned)u) << 16; return v.f;
}

// ---- workspace layout (u16 units unless noted) ----
#define BP_OFF   0          // 81920 u16 : packed [512x160] fused first-layer W, bf16 frag layout
#define BP1_OFF  81920      // 20480 u16 : packed hw1_w1 [40->64 pad][320]
#define BP2_OFF  102400     // 3072 u16  : packed hw2_w1 [40->64 pad][40->48 pad]
#define BIAS0_BYTE 210944   // 160 f32   : fused first-layer bias [h1_b|b1_b|h2_b|hb_b]

__global__ void prep_kernel(const float* __restrict__ hw1_w0, const float* __restrict__ hb1_w,
                            const float* __restrict__ hw2_w0, const float* __restrict__ hb2_w0,
                            const float* __restrict__ hw1_w1, const float* __restrict__ hw2_w1,
                            const float* __restrict__ hw1_b0, const float* __restrict__ hb1_b,
                            const float* __restrict__ hw2_b0, const float* __restrict__ hb2_b0,
                            unsigned short* __restrict__ ws16, float* __restrict__ bias0) {
    int idx = blockIdx.x * blockDim.x + threadIdx.x;
    if (idx < 81920) {
        // Bp[((nt*16+kt)*64 + l)*8 + i] = Wc[kt*32+(l>>4)*8+i][nt*16+(l&15)]
        int i = idx & 7, l = (idx >> 3) & 63, t = idx >> 9;
        int kt = t & 15, nt = t >> 4;
        int k = kt * 32 + (l >> 4) * 8 + i;
        int n = nt * 16 + (l & 15);
        int seg = n / 40, c = n - seg * 40;
        const float* src = (seg == 0) ? hw1_w0 : (seg == 1) ? hb1_w : (seg == 2) ? hw2_w0 : hb2_w0;
        ws16[BP_OFF + idx] = f2bf(src[k * 40 + c]);
    } else if (idx < 81920 + 20480) {
        int j = idx - 81920;
        int i = j & 7, l = (j >> 3) & 63, t = j >> 9;   // t = nt1*2 + kt, t<40
        int kt = t & 1, nt = t >> 1;
        int k = kt * 32 + (l >> 4) * 8 + i;
        int n = nt * 16 + (l & 15);
        float v = (k < 40) ? hw1_w1[k * 320 + n] : 0.f;
        ws16[BP1_OFF + j] = f2bf(v);
    } else if (idx < 81920 + 20480 + 3072) {
        int j = idx - 102400;
        int i = j & 7, l = (j >> 3) & 63, t = j >> 9;   // t = nt2*2 + kt, t<6
        int kt = t & 1, nt = t >> 1;
        int k = kt * 32 + (l >> 4) * 8 + i;
        int n = nt * 16 + (l & 15);
        float v = (k < 40 && n < 40) ? hw2_w1[k * 40 + n] : 0.f;
        ws16[BP2_OFF + j] = f2bf(v);
    } else if (idx < 81920 + 20480 + 3072 + 160) {
        int j = idx - 105472;
        int seg = j / 40, c = j - seg * 40;
        const float* b = (seg == 0) ? hw1_b0 : (seg == 1) ? hb1_b : (seg == 2) ? hw2_b0 : hb2_b0;
        bias0[j] = b[c];
    }
}

// ---- LDS layout (bytes) ----
#define REG0      0        // 32768: stage1 s_bf u16[32][512] (swizzled) / stage2 W1 bf16[32][320]
#define P_OFF     32768    // 20992: f32[32][164]  (pad 164 -> bank-shift 16 per 4-row group)
#define H1_OFF    53760    // 4096 : u16[32][64] swizzled (h1, K-padded)
#define H2_OFF    57856    // 4096 : u16[32][64] swizzled (h2)  / aliased later: PR f32[320]
#define W2_OFF    61952    // 2560 : u16[32][40]
#define B2_OFF    64512    // 128  : f32[32]
#define SMEM_BYTES 64640

__global__ __launch_bounds__(NTHREADS) void qmix_kernel(
    const float* __restrict__ q_values, const float* __restrict__ states,
    const unsigned short* __restrict__ Bp, const unsigned short* __restrict__ Bp1,
    const unsigned short* __restrict__ Bp2, const float* __restrict__ bias0,
    const float* __restrict__ hw1_b1, const float* __restrict__ hw2_b1,
    const float* __restrict__ hb2_w1, const float* __restrict__ hb2_b1,
    float* __restrict__ out)
{
    __shared__ __align__(16) char smem[SMEM_BYTES];
    const int tid = threadIdx.x;
    const int wv = tid >> 6;
    const int l = tid & 63;
    const int row0 = blockIdx.x * BROWS;

    // ---- phase 0: stage s tile (32x512 fp32 -> bf16 LDS, XOR-swizzled) ----
    {
        const float4* sg = (const float4*)(states + (size_t)row0 * SS);
        for (int idx = tid; idx < BROWS * (SS / 4); idx += NTHREADS) {
            int r = idx >> 7;                  // 128 float4 per row
            int c4 = idx & 127;
            float4 v = sg[idx];
            ushort4 b;
            b.x = f2bf(v.x); b.y = f2bf(v.y); b.z = f2bf(v.z); b.w = f2bf(v.w);
            int byte = (r * 1024 + c4 * 8) ^ ((r & 7) << 4);
            *(ushort4*)(smem + byte) = b;
        }
    }
    __syncthreads();

    // ---- phase 1: P[32][160] = s @ Wc via MFMA 16x16x32 bf16 ----
    f32x4 acc[2][2] = {};
    {
        const int kch = (l >> 4) * 16;         // byte offset of lane's k-chunk
        const int r0 = (l & 15);
        const int r1 = r0 + 16;
        const int swz0 = (r0 & 7) << 4;
        const unsigned short* bp0 = Bp + (size_t)((wv * 2 + 0) * 16) * 512 + (size_t)l * 8;
        const unsigned short* bp1 = Bp + (size_t)((wv * 2 + 1) * 16) * 512 + (size_t)l * 8;
        #pragma unroll
        for (int kt = 0; kt < 16; ++kt) {
            bf16x8 a0 = *(const bf16x8*)(smem + ((r0 * 1024 + kt * 64 + kch) ^ swz0));
            bf16x8 a1 = *(const bf16x8*)(smem + ((r1 * 1024 + kt * 64 + kch) ^ swz0));
            bf16x8 b0 = *(const bf16x8*)(bp0 + kt * 512);
            bf16x8 b1 = *(const bf16x8*)(bp1 + kt * 512);
            acc[0][0] = __builtin_amdgcn_mfma_f32_16x16x32_bf16(a0, b0, acc[0][0], 0, 0, 0);
            acc[0][1] = __builtin_amdgcn_mfma_f32_16x16x32_bf16(a0, b1, acc[0][1], 0, 0, 0);
            acc[1][0] = __builtin_amdgcn_mfma_f32_16x16x32_bf16(a1, b0, acc[1][0], 0, 0, 0);
            acc[1][1] = __builtin_amdgcn_mfma_f32_16x16x32_bf16(a1, b1, acc[1][1], 0, 0, 0);
        }
    }
    {
        float* P = (float*)(smem + P_OFF);
        #pragma unroll
        for (int mt = 0; mt < 2; ++mt)
        #pragma unroll
        for (int ntl = 0; ntl < 2; ++ntl)
        #pragma unroll
        for (int g = 0; g < 4; ++g) {
            int row = mt * 16 + (l >> 4) * 4 + g;
            int col = wv * 32 + ntl * 16 + (l & 15);
            P[row * 164 + col] = acc[mt][ntl][g];
        }
    }
    __syncthreads();

    // ---- phase 2: bias + activation in place ----
    {
        float* P = (float*)(smem + P_OFF);
        for (int idx = tid; idx < BROWS * N1; idx += NTHREADS) {
            int r = idx / N1, c = idx - r * N1;
            float v = P[r * 164 + c] + bias0[c];
            if ((unsigned)(c - 40) >= 40u) v = fmaxf(v, 0.f);  // relu all segs except b1
            P[r * 164 + c] = v;
        }
    }
    __syncthreads();

    // ---- phase 3: h1/h2 -> bf16 frag LDS (K pad to 64); b2 per row ----
    {
        float* P = (float*)(smem + P_OFF);
        char* H1 = smem + H1_OFF;
        char* H2 = smem + H2_OFF;
        for (int idx = tid; idx < BROWS * 64; idx += NTHREADS) {
            int r = idx >> 6, j = idx & 63;
            float v1 = (j < 40) ? P[r * 164 + j] : 0.f;
            float v2 = (j < 40) ? P[r * 164 + 80 + j] : 0.f;
            int byte = (r * 128 + j * 2) ^ ((r & 7) << 4);
            *(unsigned short*)(H1 + byte) = f2bf(v1);
            *(unsigned short*)(H2 + byte) = f2bf(v2);
        }
        if (tid < 32) {
            float s = hb2_b1[0];
            #pragma unroll 8
            for (int j = 0; j < 40; ++j) s += P[tid * 164 + 120 + j] * hb2_w1[j];
            ((float*)(smem + B2_OFF))[tid] = s;
        }
    }
    __syncthreads();

    // ---- phase 4: w1 = abs(h1 @ hw1_w1 + b) via MFMA; w2 likewise ----
    {
        char* H1 = smem + H1_OFF;
        const int kch = (l >> 4) * 16;
        f32x4 wacc[2][4] = {};
        #pragma unroll
        for (int kt = 0; kt < 2; ++kt) {
            bf16x8 a[2];
            #pragma unroll
            for (int mt = 0; mt < 2; ++mt) {
                int row = mt * 16 + (l & 15);
                a[mt] = *(const bf16x8*)(H1 + ((row * 128 + kt * 64 + kch) ^ ((row & 7) << 4)));
            }
            #pragma unroll
            for (int t = 0; t < 4; ++t) {
                int nt1 = wv * 4 + t;
                bf16x8 b = *(const bf16x8*)(Bp1 + ((size_t)(nt1 * 2 + kt) * 64 + l) * 8);
                wacc[0][t] = __builtin_amdgcn_mfma_f32_16x16x32_bf16(a[0], b, wacc[0][t], 0, 0, 0);
                wacc[1][t] = __builtin_amdgcn_mfma_f32_16x16x32_bf16(a[1], b, wacc[1][t], 0, 0, 0);
            }
        }
        unsigned short* W1 = (unsigned short*)(smem + REG0);
        #pragma unroll
        for (int mt = 0; mt < 2; ++mt)
        #pragma unroll
        for (int t = 0; t < 4; ++t)
        #pragma unroll
        for (int g = 0; g < 4; ++g) {
            int row = mt * 16 + (l >> 4) * 4 + g;
            int n = (wv * 4 + t) * 16 + (l & 15);
            W1[row * 320 + n] = f2bf(fabsf(wacc[mt][t][g] + hw1_b1[n]));
        }
        if (wv < 3) {
            char* H2 = smem + H2_OFF;
            f32x4 c2[2] = {};
            #pragma unroll
            for (int kt = 0; kt < 2; ++kt) {
                bf16x8 a[2];
                #pragma unroll
                for (int mt = 0; mt < 2; ++mt) {
                    int row = mt * 16 + (l & 15);
                    a[mt] = *(const bf16x8*)(H2 + ((row * 128 + kt * 64 + kch) ^ ((row & 7) << 4)));
                }
                bf16x8 b = *(const bf16x8*)(Bp2 + ((size_t)(wv * 2 + kt) * 64 + l) * 8);
                c2[0] = __builtin_amdgcn_mfma_f32_16x16x32_bf16(a[0], b, c2[0], 0, 0, 0);
                c2[1] = __builtin_amdgcn_mfma_f32_16x16x32_bf16(a[1], b, c2[1], 0, 0, 0);
            }
            unsigned short* W2 = (unsigned short*)(smem + W2_OFF);
            #pragma unroll
            for (int mt = 0; mt < 2; ++mt)
            #pragma unroll
            for (int g = 0; g < 4; ++g) {
                int row = mt * 16 + (l >> 4) * 4 + g;
                int n = wv * 16 + (l & 15);
                if (n < 40) W2[row * 40 + n] = f2bf(fabsf(c2[mt][g] + hw2_b1[n]));
            }
        }
    }
    __syncthreads();

    // ---- phase 5: hidden = elu(q @ w1 + b1); q_total partials ----
    {
        float* P = (float*)(smem + P_OFF);
        unsigned short* W1 = (unsigned short*)(smem + REG0);
        unsigned short* W2 = (unsigned short*)(smem + W2_OFF);
        float* PR = (float*)(smem + H2_OFF);           // H2 dead now
        int r = tid / 10;
        int hb_ = tid - r * 10;
        const float4* qp = (const float4*)(q_values + (size_t)(row0 + r) * NA);
        float4 qa = qp[0], qb = qp[1];
        float qv[8] = {qa.x, qa.y, qa.z, qa.w, qb.x, qb.y, qb.z, qb.w};
        float psum = 0.f;
        #pragma unroll
        for (int kk = 0; kk < 4; ++kk) {
            int h = hb_ + kk * 10;
            float acc2 = P[r * 164 + 40 + h];          // b1
            #pragma unroll
            for (int a = 0; a < 8; ++a) acc2 += qv[a] * bf2f(W1[r * 320 + a * 40 + h]);
            float hid = (acc2 > 0.f) ? acc2 : expm1f(acc2);
            psum += hid * bf2f(W2[r * 40 + h]);
        }
        PR[tid] = psum;
    }
    __syncthreads();
    if (tid < 32) {
        float* PR = (float*)(smem + H2_OFF);
        float s = ((float*)(smem + B2_OFF))[tid];
        #pragma unroll
        for (int g = 0; g < 10; ++g) s += PR[tid * 10 + g];
        out[row0 + tid] = s;
    }
}

extern "C" void kernel_launch(void* const* d_in, const int* in_sizes, int n_in,
                              void* d_out, int out_size, void* d_ws, size_t ws_size,
                              hipStream_t stream) {
    const float* q_values = (const float*)d_in[0];
    const float* states   = (const float*)d_in[1];
    const float* hw1_w0 = (const float*)d_in[2];
    const float* hw1_b0 = (const float*)d_in[3];
    const float* hw1_w1 = (const float*)d_in[4];
    const float* hw1_b1 = (const float*)d_in[5];
    const float* hw2_w0 = (const float*)d_in[6];
    const float* hw2_b0 = (const float*)d_in[7];
    const float* hw2_w1 = (const float*)d_in[8];
    const float* hw2_b1 = (const float*)d_in[9];
    const float* hb1_w  = (const float*)d_in[10];
    const float* hb1_b  = (const float*)d_in[11];
    const float* hb2_w0 = (const float*)d_in[12];
    const float* hb2_b0 = (const float*)d_in[13];
    const float* hb2_w1 = (const float*)d_in[14];
    const float* hb2_b1 = (const float*)d_in[15];

    unsigned short* ws16 = (unsigned short*)d_ws;
    float* bias0 = (float*)((char*)d_ws + BIAS0_BYTE);

    const int prep_total = 81920 + 20480 + 3072 + 160;
    prep_kernel<<<(prep_total + 255) / 256, 256, 0, stream>>>(
        hw1_w0, hb1_w, hw2_w0, hb2_w0, hw1_w1, hw2_w1,
        hw1_b0, hb1_b, hw2_b0, hb2_b0, ws16, bias0);

    const int B = in_sizes[0] / NA;   // 65536 rows
    qmix_kernel<<<B / BROWS, NTHREADS, 0, stream>>>(
        q_values, states,
        ws16 + BP_OFF, ws16 + BP1_OFF, ws16 + BP2_OFF, bias0,
        hw1_b1, hw2_b1, hb2_w1, hb2_b1, (float*)d_out);
}

// Round 2
// 268.678 us; speedup vs baseline: 1.1403x; 1.1403x over previous
//
#include <hip/hip_runtime.h>
#include <math.h>

#define NA 8
#define SS 512
#define BROWS 32
#define NTHREADS 320

typedef __attribute__((ext_vector_type(8))) short bf16x8;
typedef __attribute__((ext_vector_type(4))) float f32x4;

static __device__ __forceinline__ unsigned short f2bf(float f) {
    union { float f; unsigned u; } v; v.f = f;
    unsigned r = v.u + 0x7FFFu + ((v.u >> 16) & 1u);
    return (unsigned short)(r >> 16);
}
static __device__ __forceinline__ float bf2f(unsigned short u) {
    union { unsigned u; float f; } v; v.u = ((unsigned)u) << 16; return v.f;
}

// ---- workspace layout (u16 units unless noted) ----
#define BP_OFF   0          // 81920 u16 : packed [512x160] fused first-layer W, bf16 frag layout
#define BP1_OFF  81920      // 20480 u16 : packed hw1_w1 [40->64 pad][320]
#define BP2_OFF  102400     // 3072 u16  : packed hw2_w1 [40->64 pad][40->48 pad]
#define BIAS0_BYTE 210944   // 160 f32   : fused first-layer bias [h1_b|b1_b|h2_b|hb_b]

__global__ void prep_kernel(const float* __restrict__ hw1_w0, const float* __restrict__ hb1_w,
                            const float* __restrict__ hw2_w0, const float* __restrict__ hb2_w0,
                            const float* __restrict__ hw1_w1, const float* __restrict__ hw2_w1,
                            const float* __restrict__ hw1_b0, const float* __restrict__ hb1_b,
                            const float* __restrict__ hw2_b0, const float* __restrict__ hb2_b0,
                            unsigned short* __restrict__ ws16, float* __restrict__ bias0) {
    int idx = blockIdx.x * blockDim.x + threadIdx.x;
    if (idx < 81920) {
        // Bp[((nt*16+kt)*64 + l)*8 + i] = Wc[kt*32+(l>>4)*8+i][nt*16+(l&15)]
        int i = idx & 7, l = (idx >> 3) & 63, t = idx >> 9;
        int kt = t & 15, nt = t >> 4;
        int k = kt * 32 + (l >> 4) * 8 + i;
        int n = nt * 16 + (l & 15);
        int seg = n / 40, c = n - seg * 40;
        const float* src = (seg == 0) ? hw1_w0 : (seg == 1) ? hb1_w : (seg == 2) ? hw2_w0 : hb2_w0;
        ws16[BP_OFF + idx] = f2bf(src[k * 40 + c]);
    } else if (idx < 81920 + 20480) {
        int j = idx - 81920;
        int i = j & 7, l = (j >> 3) & 63, t = j >> 9;   // t = nt1*2 + kt, t<40
        int kt = t & 1, nt = t >> 1;
        int k = kt * 32 + (l >> 4) * 8 + i;
        int n = nt * 16 + (l & 15);
        float v = (k < 40) ? hw1_w1[k * 320 + n] : 0.f;
        ws16[BP1_OFF + j] = f2bf(v);
    } else if (idx < 81920 + 20480 + 3072) {
        int j = idx - 102400;
        int i = j & 7, l = (j >> 3) & 63, t = j >> 9;   // t = nt2*2 + kt, t<6
        int kt = t & 1, nt = t >> 1;
        int k = kt * 32 + (l >> 4) * 8 + i;
        int n = nt * 16 + (l & 15);
        float v = (k < 40 && n < 40) ? hw2_w1[k * 40 + n] : 0.f;
        ws16[BP2_OFF + j] = f2bf(v);
    } else if (idx < 81920 + 20480 + 3072 + 160) {
        int j = idx - 105472;
        int seg = j / 40, c = j - seg * 40;
        const float* b = (seg == 0) ? hw1_b0 : (seg == 1) ? hb1_b : (seg == 2) ? hw2_b0 : hb2_b0;
        bias0[j] = b[c];
    }
}

// ---- LDS layout (bytes) ----
// SBUF 0..32767 : stage1 s_bf u16[32][512] swizzled; reused in phase 4/5 as W1 u16[32][324]
#define W1_STRIDE 324
#define B1_OFF    32768   // 5632 : f32[32][44]  (b1 segment)
#define H1_OFF    38400   // 4096 : u16[32][64] swizzled (h1, K-pad)  / phase5: PR f32[320]
#define H2_OFF    42496   // 4096 : u16[32][64] swizzled (h2)
#define W2_OFF    46592   // 2560 : u16[32][40]
#define B2_OFF    49152   // 256  : f32[2][32] (b2 partials from waves 3,4)
#define SMEM_BYTES 49408

__global__ __launch_bounds__(NTHREADS, 4) void qmix_kernel(
    const float* __restrict__ q_values, const float* __restrict__ states,
    const unsigned short* __restrict__ Bp, const unsigned short* __restrict__ Bp1,
    const unsigned short* __restrict__ Bp2, const float* __restrict__ bias0,
    const float* __restrict__ hw1_b1, const float* __restrict__ hw2_b1,
    const float* __restrict__ hb2_w1, const float* __restrict__ hb2_b1,
    float* __restrict__ out)
{
    __shared__ __align__(16) char smem[SMEM_BYTES];
    const int tid = threadIdx.x;
    const int wv = tid >> 6;
    const int l = tid & 63;
    const int p = l & 15;
    const int row0 = blockIdx.x * BROWS;

    // ---- phase 0: stage s tile (32x512 fp32 -> bf16 LDS, XOR-swizzled); zero H1/H2 K-pad ----
    {
        const float4* sg = (const float4*)(states + (size_t)row0 * SS);
        for (int idx = tid; idx < BROWS * (SS / 4); idx += NTHREADS) {
            int r = idx >> 7;                  // 128 float4 per row
            int c4 = idx & 127;
            float4 v = sg[idx];
            ushort4 b;
            b.x = f2bf(v.x); b.y = f2bf(v.y); b.z = f2bf(v.z); b.w = f2bf(v.w);
            int byte = (r * 1024 + c4 * 8) ^ ((r & 7) << 4);
            *(ushort4*)(smem + byte) = b;
        }
        for (int idx = tid; idx < 32 * 24; idx += NTHREADS) {
            int r = idx / 24, k = 40 + (idx - r * 24);
            int byte = (r * 128 + k * 2) ^ ((r & 7) << 4);
            *(unsigned short*)(smem + H1_OFF + byte) = 0;
            *(unsigned short*)(smem + H2_OFF + byte) = 0;
        }
    }
    __syncthreads();

    // ---- phase 1: P[32][160] = s @ Wc via MFMA 16x16x32 bf16 ----
    f32x4 acc[2][2] = {};
    {
        const int kch = (l >> 4) * 16;         // byte offset of lane's k-chunk
        const int r0 = p;
        const int r1 = r0 + 16;
        const int swz0 = (r0 & 7) << 4;
        const unsigned short* bp0 = Bp + (size_t)((wv * 2 + 0) * 16) * 512 + (size_t)l * 8;
        const unsigned short* bp1 = Bp + (size_t)((wv * 2 + 1) * 16) * 512 + (size_t)l * 8;
        #pragma unroll
        for (int kt = 0; kt < 16; ++kt) {
            bf16x8 a0 = *(const bf16x8*)(smem + ((r0 * 1024 + kt * 64 + kch) ^ swz0));
            bf16x8 a1 = *(const bf16x8*)(smem + ((r1 * 1024 + kt * 64 + kch) ^ swz0));
            bf16x8 b0 = *(const bf16x8*)(bp0 + kt * 512);
            bf16x8 b1 = *(const bf16x8*)(bp1 + kt * 512);
            acc[0][0] = __builtin_amdgcn_mfma_f32_16x16x32_bf16(a0, b0, acc[0][0], 0, 0, 0);
            acc[0][1] = __builtin_amdgcn_mfma_f32_16x16x32_bf16(a0, b1, acc[0][1], 0, 0, 0);
            acc[1][0] = __builtin_amdgcn_mfma_f32_16x16x32_bf16(a1, b0, acc[1][0], 0, 0, 0);
            acc[1][1] = __builtin_amdgcn_mfma_f32_16x16x32_bf16(a1, b1, acc[1][1], 0, 0, 0);
        }
    }

    // ---- phase 1 epilogue: bias+act in-register, scatter to H1/H2/b1; b2 partials in-register ----
    {
        float rs[2][4] = {{0.f,0.f,0.f,0.f},{0.f,0.f,0.f,0.f}};
        float* b1buf = (float*)(smem + B1_OFF);
        #pragma unroll
        for (int ntl = 0; ntl < 2; ++ntl) {
            const int c = wv * 32 + ntl * 16 + p;
            const float bia = bias0[c];
            const float hbw = (c >= 120) ? hb2_w1[c - 120] : 0.f;
            #pragma unroll
            for (int mt = 0; mt < 2; ++mt)
            #pragma unroll
            for (int g = 0; g < 4; ++g) {
                const int row = mt * 16 + (l >> 4) * 4 + g;
                const float v = acc[mt][ntl][g] + bia;
                if (c < 40) {
                    *(unsigned short*)(smem + H1_OFF + ((row * 128 + c * 2) ^ ((row & 7) << 4)))
                        = f2bf(fmaxf(v, 0.f));
                } else if (c < 80) {
                    b1buf[row * 44 + (c - 40)] = v;
                } else if (c < 120) {
                    *(unsigned short*)(smem + H2_OFF + ((row * 128 + (c - 80) * 2) ^ ((row & 7) << 4)))
                        = f2bf(fmaxf(v, 0.f));
                } else {
                    rs[mt][g] += fmaxf(v, 0.f) * hbw;
                }
            }
        }
        if (wv >= 3) {
            float* B2 = (float*)(smem + B2_OFF);
            #pragma unroll
            for (int mt = 0; mt < 2; ++mt)
            #pragma unroll
            for (int g = 0; g < 4; ++g) {
                float r2 = rs[mt][g];
                r2 += __shfl_xor(r2, 1);
                r2 += __shfl_xor(r2, 2);
                r2 += __shfl_xor(r2, 4);
                r2 += __shfl_xor(r2, 8);
                if (p == 0) B2[(wv - 3) * 32 + mt * 16 + (l >> 4) * 4 + g] = r2;
            }
        }
    }
    __syncthreads();

    // ---- phase 4: w1 = abs(h1 @ hw1_w1 + b) via MFMA; w2 likewise ----
    {
        char* H1 = smem + H1_OFF;
        const int kch = (l >> 4) * 16;
        f32x4 wacc[2][4] = {};
        #pragma unroll
        for (int kt = 0; kt < 2; ++kt) {
            bf16x8 a[2];
            #pragma unroll
            for (int mt = 0; mt < 2; ++mt) {
                int row = mt * 16 + p;
                a[mt] = *(const bf16x8*)(H1 + ((row * 128 + kt * 64 + kch) ^ ((row & 7) << 4)));
            }
            #pragma unroll
            for (int t = 0; t < 4; ++t) {
                int nt1 = wv * 4 + t;
                bf16x8 b = *(const bf16x8*)(Bp1 + ((size_t)(nt1 * 2 + kt) * 64 + l) * 8);
                wacc[0][t] = __builtin_amdgcn_mfma_f32_16x16x32_bf16(a[0], b, wacc[0][t], 0, 0, 0);
                wacc[1][t] = __builtin_amdgcn_mfma_f32_16x16x32_bf16(a[1], b, wacc[1][t], 0, 0, 0);
            }
        }
        unsigned short* W1 = (unsigned short*)smem;     // s-tile dead, reuse
        #pragma unroll
        for (int mt = 0; mt < 2; ++mt)
        #pragma unroll
        for (int t = 0; t < 4; ++t)
        #pragma unroll
        for (int g = 0; g < 4; ++g) {
            int row = mt * 16 + (l >> 4) * 4 + g;
            int n = (wv * 4 + t) * 16 + p;
            W1[row * W1_STRIDE + n] = f2bf(fabsf(wacc[mt][t][g] + hw1_b1[n]));
        }
        if (wv < 3) {
            char* H2 = smem + H2_OFF;
            f32x4 c2[2] = {};
            #pragma unroll
            for (int kt = 0; kt < 2; ++kt) {
                bf16x8 a[2];
                #pragma unroll
                for (int mt = 0; mt < 2; ++mt) {
                    int row = mt * 16 + p;
                    a[mt] = *(const bf16x8*)(H2 + ((row * 128 + kt * 64 + kch) ^ ((row & 7) << 4)));
                }
                bf16x8 b = *(const bf16x8*)(Bp2 + ((size_t)(wv * 2 + kt) * 64 + l) * 8);
                c2[0] = __builtin_amdgcn_mfma_f32_16x16x32_bf16(a[0], b, c2[0], 0, 0, 0);
                c2[1] = __builtin_amdgcn_mfma_f32_16x16x32_bf16(a[1], b, c2[1], 0, 0, 0);
            }
            unsigned short* W2 = (unsigned short*)(smem + W2_OFF);
            #pragma unroll
            for (int mt = 0; mt < 2; ++mt)
            #pragma unroll
            for (int g = 0; g < 4; ++g) {
                int row = mt * 16 + (l >> 4) * 4 + g;
                int n = wv * 16 + p;
                if (n < 40) W2[row * 40 + n] = f2bf(fabsf(c2[mt][g] + hw2_b1[n]));
            }
        }
    }
    __syncthreads();

    // ---- phase 5: hidden = elu(q @ w1 + b1); q_total partials ----
    {
        float* b1buf = (float*)(smem + B1_OFF);
        unsigned short* W1 = (unsigned short*)smem;
        unsigned short* W2 = (unsigned short*)(smem + W2_OFF);
        float* PR = (float*)(smem + H1_OFF);           // H1 dead now
        int r = tid / 10;
        int hb_ = tid - r * 10;
        const float4* qp = (const float4*)(q_values + (size_t)(row0 + r) * NA);
        float4 qa = qp[0], qb = qp[1];
        float qv[8] = {qa.x, qa.y, qa.z, qa.w, qb.x, qb.y, qb.z, qb.w};
        float psum = 0.f;
        #pragma unroll
        for (int kk = 0; kk < 4; ++kk) {
            int h = hb_ + kk * 10;
            float acc2 = b1buf[r * 44 + h];            // b1
            #pragma unroll
            for (int a = 0; a < 8; ++a) acc2 += qv[a] * bf2f(W1[r * W1_STRIDE + a * 40 + h]);
            float hid = (acc2 > 0.f) ? acc2 : expm1f(acc2);
            psum += hid * bf2f(W2[r * 40 + h]);
        }
        PR[tid] = psum;
    }
    __syncthreads();
    if (tid < 32) {
        float* PR = (float*)(smem + H1_OFF);
        float* B2 = (float*)(smem + B2_OFF);
        float s = B2[tid] + B2[32 + tid] + hb2_b1[0];
        #pragma unroll
        for (int g = 0; g < 10; ++g) s += PR[tid * 10 + g];
        out[row0 + tid] = s;
    }
}

extern "C" void kernel_launch(void* const* d_in, const int* in_sizes, int n_in,
                              void* d_out, int out_size, void* d_ws, size_t ws_size,
                              hipStream_t stream) {
    const float* q_values = (const float*)d_in[0];
    const float* states   = (const float*)d_in[1];
    const float* hw1_w0 = (const float*)d_in[2];
    const float* hw1_b0 = (const float*)d_in[3];
    const float* hw1_w1 = (const float*)d_in[4];
    const float* hw1_b1 = (const float*)d_in[5];
    const float* hw2_w0 = (const float*)d_in[6];
    const float* hw2_b0 = (const float*)d_in[7];
    const float* hw2_w1 = (const float*)d_in[8];
    const float* hw2_b1 = (const float*)d_in[9];
    const float* hb1_w  = (const float*)d_in[10];
    const float* hb1_b  = (const float*)d_in[11];
    const float* hb2_w0 = (const float*)d_in[12];
    const float* hb2_b0 = (const float*)d_in[13];
    const float* hb2_w1 = (const float*)d_in[14];
    const float* hb2_b1 = (const float*)d_in[15];

    unsigned short* ws16 = (unsigned short*)d_ws;
    float* bias0 = (float*)((char*)d_ws + BIAS0_BYTE);

    const int prep_total = 81920 + 20480 + 3072 + 160;
    prep_kernel<<<(prep_total + 255) / 256, 256, 0, stream>>>(
        hw1_w0, hb1_w, hw2_w0, hb2_w0, hw1_w1, hw2_w1,
        hw1_b0, hb1_b, hw2_b0, hb2_b0, ws16, bias0);

    const int B = in_sizes[0] / NA;   // 65536 rows
    qmix_kernel<<<B / BROWS, NTHREADS, 0, stream>>>(
        q_values, states,
        ws16 + BP_OFF, ws16 + BP1_OFF, ws16 + BP2_OFF, bias0,
        hw1_b1, hw2_b1, hb2_w1, hb2_b1, (float*)d_out);
}